// Round 1
// baseline (1485.214 us; speedup 1.0000x reference)
//
#include <hip/hip_runtime.h>
#include <math.h>

#define NB 16    // batch
#define SS 256   // spatial size (H = W = 256)
#define DV 32    // channels
#define MM 12    // ky modes kept
#define MK 24    // kx modes kept (0..11 and 244..255)
#define LL 4     // layers

// Workspace layout (floats):
//   h : [NB][DV][SS][SS]              (in-place updated per layer)
//   A : [NB][MM(ky)][DV][SS(iy)][2]   (forward ky-DFT of h rows)
//   g : [NB][MM(ky)][DV][SS(iy)][2]   (inverse kx-DFT of mixed modes)

__device__ __forceinline__ void make_tw(float* tw_c, float* tw_s) {
    int tid = threadIdx.x;
    float ang = 0.024543692606170259679f * (float)tid;  // 2*pi/256
    float s, c;
    sincosf(ang, &s, &c);
    tw_c[tid] = c;
    tw_s[tid] = s;
}

// Lifting: h0[b,c,iy,j] = p_w[c,0]*x + p_w[c,1]*gy(iy) + p_w[c,2]*gx(j) + p_b[c]
// Also emits A0 = ky-DFT of each row.
__global__ __launch_bounds__(256) void k_lift(const float* __restrict__ x,
        const float* __restrict__ p_w, const float* __restrict__ p_b,
        float* __restrict__ h, float* __restrict__ A)
{
    __shared__ float row[DV][SS + 1];
    __shared__ float tw_c[SS], tw_s[SS];
    int tid = threadIdx.x;
    int b  = blockIdx.x >> 8;
    int iy = blockIdx.x & 255;
    make_tw(tw_c, tw_s);

    float xv = x[((size_t)b * SS + iy) * SS + tid];
    float gy = -1.0f + 2.0f * (float)iy  * (1.0f / 255.0f);
    float gx = -1.0f + 2.0f * (float)tid * (1.0f / 255.0f);

    float* hb = h + ((size_t)b * DV * SS + iy) * SS;
    for (int c = 0; c < DV; ++c) {
        float v = p_w[3*c] * xv + p_w[3*c + 1] * gy + p_w[3*c + 2] * gx + p_b[c];
        row[c][tid] = v;
        hb[(size_t)c * SS * SS + tid] = v;
    }
    __syncthreads();

    for (int idx = tid; idx < DV * MM; idx += 256) {
        int c = idx / MM, ky = idx % MM;
        float sr = 0.f, si = 0.f;
        for (int j = 0; j < SS; ++j) {
            int t = (ky * j) & 255;
            float v = row[c][j];
            sr += v * tw_c[t];
            si -= v * tw_s[t];
        }
        size_t o = ((((size_t)b * MM + ky) * DV + c) * SS + iy) * 2;
        A[o] = sr; A[o + 1] = si;
    }
}

// Per (b,ky): kx-DFT over iy (24 modes) -> channel mix with W1/W2 -> inverse kx-DFT.
__global__ __launch_bounds__(256) void k_modes(const float* __restrict__ A,
        const float* __restrict__ w1r, const float* __restrict__ w1i,
        const float* __restrict__ w2r, const float* __restrict__ w2i,
        float* __restrict__ g, int l)
{
    __shared__ float Abuf[DV][SS * 2 + 2];
    __shared__ float Fin[DV][MK * 2];
    __shared__ float Fout[DV][MK * 2];
    __shared__ float tw_c[SS], tw_s[SS];
    int tid = threadIdx.x;
    int b  = blockIdx.x / MM;
    int ky = blockIdx.x % MM;
    make_tw(tw_c, tw_s);

    const float* Ab = A + (((size_t)b * MM + ky) * DV) * SS * 2;
    for (int k = tid; k < DV * SS * 2; k += 256) {
        int c = k >> 9;
        int r = k & 511;
        Abuf[c][r] = Ab[k];
    }
    __syncthreads();

    // forward DFT along h:  F = sum_iy A * e^{-i 2pi f iy/256}
    for (int idx = tid; idx < DV * MK; idx += 256) {
        int c = idx / MK, m = idx % MK;
        int freq = (m < MM) ? m : (232 + m);   // 244..255 for m=12..23
        float fr = 0.f, fi = 0.f;
        for (int iy = 0; iy < SS; ++iy) {
            int t = (freq * iy) & 255;
            float ar = Abuf[c][iy * 2], ai = Abuf[c][iy * 2 + 1];
            float cc = tw_c[t], sn = tw_s[t];
            fr += ar * cc + ai * sn;
            fi += ai * cc - ar * sn;
        }
        Fin[c][m * 2] = fr; Fin[c][m * 2 + 1] = fi;
    }
    __syncthreads();

    // channel mixing: out[o] = sum_i F[i] * W[i,o]   (complex)
    // W layout: [l][i][o][x][y], x in [0,12), y = ky
    float scale = ((ky == 0) ? 1.0f : 2.0f) * (1.0f / 65536.0f);
    for (int idx = tid; idx < DV * MK; idx += 256) {
        int o = idx / MK, m = idx % MK;
        const float* Wr; const float* Wi; int xm;
        if (m < MM) { Wr = w1r; Wi = w1i; xm = m; }
        else        { Wr = w2r; Wi = w2i; xm = m - MM; }
        size_t wbase = ((size_t)l * DV * DV + o) * (MM * MM) + xm * MM + ky;
        float orr = 0.f, oii = 0.f;
        for (int i = 0; i < DV; ++i) {
            float fr = Fin[i][m * 2], fi = Fin[i][m * 2 + 1];
            size_t wi = wbase + (size_t)i * DV * MM * MM;
            float wr = Wr[wi], wim = Wi[wi];
            orr += fr * wr - fi * wim;
            oii += fr * wim + fi * wr;
        }
        Fout[o][m * 2] = orr * scale;
        Fout[o][m * 2 + 1] = oii * scale;
    }
    __syncthreads();

    // inverse DFT along h: g = sum_m Fout * e^{+i 2pi f iy/256}
    float* gb = g + (((size_t)b * MM + ky) * DV) * SS * 2;
    for (int idx = tid; idx < DV * SS; idx += 256) {
        int c = idx >> 8, iy = idx & 255;
        float gr = 0.f, gi = 0.f;
        #pragma unroll
        for (int m = 0; m < MK; ++m) {
            int freq = (m < MM) ? m : (232 + m);
            int t = (freq * iy) & 255;
            float cc = tw_c[t], sn = tw_s[t];
            float fr = Fout[c][m * 2], fi = Fout[c][m * 2 + 1];
            gr += fr * cc - fi * sn;
            gi += fr * sn + fi * cc;
        }
        gb[((size_t)c * SS + iy) * 2]     = gr;
        gb[((size_t)c * SS + iy) * 2 + 1] = gi;
    }
}

// One block per (b,row): h_next = relu( conv1x1(h) + irfft_w(g) ), in place.
// Also emits next layer's A (ky-DFT of the new row).
template<bool RELU>
__global__ __launch_bounds__(256) void k_layer(float* __restrict__ h,
        const float* __restrict__ g, const float* __restrict__ ws_w,
        const float* __restrict__ ws_b, float* __restrict__ A, int l)
{
    __shared__ float row[DV][SS + 1];
    __shared__ float tw_c[SS], tw_s[SS];
    int tid = threadIdx.x;
    int b  = blockIdx.x >> 8;
    int iy = blockIdx.x & 255;
    make_tw(tw_c, tw_s);

    float* hb = h + ((size_t)b * DV * SS + iy) * SS;
    float hval[DV];
    #pragma unroll
    for (int c = 0; c < DV; ++c)
        hval[c] = hb[(size_t)c * SS * SS + tid];
    __syncthreads();  // tw table ready (loads above are per-thread private)

    float cs[MM], sn[MM];
    #pragma unroll
    for (int ky = 0; ky < MM; ++ky) {
        int t = (ky * tid) & 255;
        cs[ky] = tw_c[t]; sn[ky] = tw_s[t];
    }

    const float* gb  = g + (size_t)b * MM * DV * SS * 2;   // [ky][c][iy][2]
    const float* wsw = ws_w + (size_t)l * DV * DV;
    const float* wsb = ws_b + (size_t)l * DV;

    for (int co = 0; co < DV; ++co) {
        float acc = wsb[co];
        #pragma unroll
        for (int ci = 0; ci < DV; ++ci)
            acc += wsw[co * DV + ci] * hval[ci];   // uniform -> scalar loads
        #pragma unroll
        for (int ky = 0; ky < MM; ++ky) {
            float gr = gb[(((size_t)ky * DV + co) * SS + iy) * 2];
            float gi = gb[(((size_t)ky * DV + co) * SS + iy) * 2 + 1];
            acc += gr * cs[ky] - gi * sn[ky];
        }
        if (RELU) acc = fmaxf(acc, 0.f);
        row[co][tid] = acc;
        hb[(size_t)co * SS * SS + tid] = acc;
    }
    __syncthreads();

    for (int idx = tid; idx < DV * MM; idx += 256) {
        int c = idx / MM, ky = idx % MM;
        float sr = 0.f, si = 0.f;
        for (int j = 0; j < SS; ++j) {
            int t = (ky * j) & 255;
            float v = row[c][j];
            sr += v * tw_c[t];
            si -= v * tw_s[t];
        }
        size_t o = ((((size_t)b * MM + ky) * DV + c) * SS + iy) * 2;
        A[o] = sr; A[o + 1] = si;
    }
}

// Last layer fused with projection: out = q_b + sum_co q_w[co]*(conv+irfft)  (no relu)
__global__ __launch_bounds__(256) void k_final(const float* __restrict__ h,
        const float* __restrict__ g, const float* __restrict__ ws_w,
        const float* __restrict__ ws_b, const float* __restrict__ q_w,
        const float* __restrict__ q_b, float* __restrict__ out, int l)
{
    __shared__ float tw_c[SS], tw_s[SS];
    int tid = threadIdx.x;
    int b  = blockIdx.x >> 8;
    int iy = blockIdx.x & 255;
    make_tw(tw_c, tw_s);

    const float* hb = h + ((size_t)b * DV * SS + iy) * SS;
    float hval[DV];
    #pragma unroll
    for (int c = 0; c < DV; ++c)
        hval[c] = hb[(size_t)c * SS * SS + tid];
    __syncthreads();

    float cs[MM], sn[MM];
    #pragma unroll
    for (int ky = 0; ky < MM; ++ky) {
        int t = (ky * tid) & 255;
        cs[ky] = tw_c[t]; sn[ky] = tw_s[t];
    }

    const float* gb  = g + (size_t)b * MM * DV * SS * 2;
    const float* wsw = ws_w + (size_t)l * DV * DV;
    const float* wsb = ws_b + (size_t)l * DV;

    float oacc = q_b[0];
    for (int co = 0; co < DV; ++co) {
        float acc = wsb[co];
        #pragma unroll
        for (int ci = 0; ci < DV; ++ci)
            acc += wsw[co * DV + ci] * hval[ci];
        #pragma unroll
        for (int ky = 0; ky < MM; ++ky) {
            float gr = gb[(((size_t)ky * DV + co) * SS + iy) * 2];
            float gi = gb[(((size_t)ky * DV + co) * SS + iy) * 2 + 1];
            acc += gr * cs[ky] - gi * sn[ky];
        }
        oacc += q_w[co] * acc;
    }
    out[((size_t)b * SS + iy) * SS + tid] = oacc;
}

extern "C" void kernel_launch(void* const* d_in, const int* in_sizes, int n_in,
                              void* d_out, int out_size, void* d_ws, size_t ws_size,
                              hipStream_t stream)
{
    const float* x    = (const float*)d_in[0];
    const float* p_w  = (const float*)d_in[1];
    const float* p_b  = (const float*)d_in[2];
    const float* ws_w = (const float*)d_in[3];
    const float* ws_b = (const float*)d_in[4];
    const float* w1r  = (const float*)d_in[5];
    const float* w1i  = (const float*)d_in[6];
    const float* w2r  = (const float*)d_in[7];
    const float* w2i  = (const float*)d_in[8];
    const float* q_w  = (const float*)d_in[9];
    const float* q_b  = (const float*)d_in[10];
    float* out = (float*)d_out;

    float* h = (float*)d_ws;
    float* A = h + (size_t)NB * DV * SS * SS;
    float* g = A + (size_t)NB * MM * DV * SS * 2;

    dim3 blk(256);
    k_lift<<<NB * SS, blk, 0, stream>>>(x, p_w, p_b, h, A);
    for (int l = 0; l < LL; ++l) {
        k_modes<<<NB * MM, blk, 0, stream>>>(A, w1r, w1i, w2r, w2i, g, l);
        if (l < LL - 1)
            k_layer<true><<<NB * SS, blk, 0, stream>>>(h, g, ws_w, ws_b, A, l);
        else
            k_final<<<NB * SS, blk, 0, stream>>>(h, g, ws_w, ws_b, q_w, q_b, out, l);
    }
}